// Round 3
// baseline (845.593 us; speedup 1.0000x reference)
//
#include <hip/hip_runtime.h>
#include <hip/hip_bf16.h>

// GraphAE: pseudo == 0 => only W[0] of the 8 spline matrices matters.
// Linearization: mean(h[src])@W2_0 == mean(h[src]@W2_0) -> project before gather.
// Round 12:
//  - Per-node CSR (scatter_edges: 60us, 53MB write-amplified) DELETED.
//    Edges are only bucket-partitioned (64-node buckets, 782 blocks) with
//    block-local chunked writes; aggregation runs per-bucket in LDS with
//    ds_add_f32 accumulators (stride 65, degree in col 64). No global
//    atomics in the hot path, no esrc/offs/invd/deg buffers.
//  - agg blocks: 782 (~3/CU) -> enough TLP to hide gather latency.
//
// Verified MFMA layouts (guide §3): A[m=lane&15][k=(lane>>4)*8+j],
// B[k=(lane>>4)*8+j][n=lane&15], D[row=(lane>>4)*4+r][col=lane&15].
// NOTE: packs src into 16 bits (N <= 65536) and dst&63 into 6 bits.

#define THREADS 256

typedef __attribute__((ext_vector_type(8))) short bf16x8;   // 8 bf16 = 4 VGPRs
typedef __attribute__((ext_vector_type(4))) float f32x4;    // acc

__device__ __forceinline__ float bf2f(unsigned short u) {
    unsigned v = ((unsigned)u) << 16;
    return __builtin_bit_cast(float, v);
}
__device__ __forceinline__ unsigned short f2bf(float f) {
    __hip_bfloat16 h = __float2bfloat16(f);   // RNE
    return __builtin_bit_cast(unsigned short, h);
}

// ---------------- weight pack ----------------
// Pack fp32 W (eff. K x NOUT) into MFMA B-frag layout bf16:
// dst[(((s*NB + j)*64 + lane)*8 + i] = W[s*32 + (lane>>4)*8 + i][j*16 + (lane&15)]
__device__ __forceinline__ void pack_one(unsigned short* dst,
                                         const float* W0, const float* W1,
                                         int NB, int ksplit, int colsplit,
                                         int ld0, int ld1, int t) {
    int i = t & 7, lane = (t >> 3) & 63, rest = t >> 9;
    int j = rest % NB, s = rest / NB;
    int k = s * 32 + ((lane >> 4) << 3) + i;
    int c = (j << 4) + (lane & 15);
    float v;
    if (c >= colsplit)    v = W1[(size_t)k * ld1 + (c - colsplit)];
    else if (k >= ksplit) v = W1[(size_t)(k - ksplit) * ld1 + c];
    else                  v = W0[(size_t)k * ld0 + c];
    dst[t] = f2bf(v);
}

#define BIG (1 << 30)

// prep: weight packs + x->bf16 (vectorized) + bucket histogram (64-node buckets)
__global__ void prep_kernel(const float* __restrict__ W1g, const float* __restrict__ root1,
                            const float* __restrict__ W2g, const float* __restrict__ root2,
                            const float* __restrict__ dw1, const float* __restrict__ dw2,
                            const float* __restrict__ x, const int* __restrict__ dstv,
                            int* __restrict__ bcnt,
                            unsigned short* __restrict__ Pb1,   // 128x256
                            unsigned short* __restrict__ Pb2,   // 256x128
                            unsigned short* __restrict__ Pd1,   // 64x256
                            unsigned short* __restrict__ Pd2,   // 256x64
                            unsigned short* __restrict__ ab1,   // N x 128, x -> cols 64:128
                            int n, int E, int pb_pack) {
    if ((int)blockIdx.x >= pb_pack) {
        __shared__ int hist[1024];
        int t = threadIdx.x;
        for (int b = t; b < 1024; b += 256) hist[b] = 0;
        __syncthreads();
        int e0 = ((int)blockIdx.x - pb_pack) * 4096;
#pragma unroll
        for (int i = 0; i < 16; ++i) {
            int e = e0 + t + i * 256;
            if (e < E) atomicAdd(&hist[dstv[e] >> 6], 1);
        }
        __syncthreads();
        for (int b = t; b < 1024; b += 256) {
            int h = hist[b];
            if (h) atomicAdd(&bcnt[b], h);
        }
        return;
    }
    int t = blockIdx.x * blockDim.x + threadIdx.x;
    if (t < 32768) {
        pack_one(Pb1, W1g, root1, 16, 64, BIG, 256, 256, t);
    } else if (t < 65536) {
        pack_one(Pb2, W2g, root2, 8, BIG, 64, 64, 64, t - 32768);
    } else if (t < 81920) {
        pack_one(Pd1, dw1, dw1, 16, BIG, BIG, 256, 256, t - 65536);
    } else if (t < 98304) {
        pack_one(Pd2, dw2, dw2, 4, BIG, BIG, 64, 64, t - 81920);
    } else if (t < 98304 + n * 16) {
        int u = t - 98304;
        int row = u >> 4, c4 = (u & 15) * 4;
        float4 v = *(const float4*)(x + (size_t)row * 64 + c4);
        unsigned lo = (unsigned)f2bf(v.x) | ((unsigned)f2bf(v.y) << 16);
        unsigned hi = (unsigned)f2bf(v.z) | ((unsigned)f2bf(v.w) << 16);
        uint2 o; o.x = lo; o.y = hi;
        *(uint2*)(ab1 + (size_t)row * 128 + 64 + c4) = o;
    }
}

// exclusive scan of bcnt[1024] -> gbase (one block, 512 threads, Hillis-Steele)
__global__ __launch_bounds__(512) void scan_buckets(
    const int* __restrict__ bcnt, int* __restrict__ gbase) {
    __shared__ int s[1024];
    int t = threadIdx.x;
    int a0 = bcnt[t], a1 = bcnt[t + 512];
    s[t] = a0; s[t + 512] = a1;
    __syncthreads();
    for (int off = 1; off < 1024; off <<= 1) {
        int v0 = (t >= off) ? s[t - off] : 0;
        int v1 = (t + 512 >= off) ? s[t + 512 - off] : 0;
        __syncthreads();
        s[t] += v0; s[t + 512] += v1;
        __syncthreads();
    }
    gbase[t] = s[t] - a0;
    gbase[t + 512] = s[t + 512] - a1;
}

// partition edges into 64-node buckets; block-local chunked writes of packed
// ((dst&63)<<16 | src). Contiguous per block per bucket -> no line bouncing.
__global__ __launch_bounds__(256) void partition_edges(
    const int* __restrict__ src, const int* __restrict__ dst,
    const int* __restrict__ gbase, int* __restrict__ bcur,
    int* __restrict__ epack, int E) {
    __shared__ int hist[1024];
    __shared__ int base[1024];
    __shared__ int lcur[1024];
    int t = threadIdx.x;
    for (int b = t; b < 1024; b += 256) { hist[b] = 0; lcur[b] = 0; }
    __syncthreads();
    int e0 = blockIdx.x * 4096;
    int myd[16], mys[16];
#pragma unroll
    for (int i = 0; i < 16; ++i) {
        int e = e0 + t + i * 256;
        int d = (e < E) ? dst[e] : -1;
        mys[i] = (e < E) ? src[e] : 0;
        myd[i] = d;
        if (d >= 0) atomicAdd(&hist[d >> 6], 1);
    }
    __syncthreads();
    for (int b = t; b < 1024; b += 256) {
        int h = hist[b];
        if (h) base[b] = gbase[b] + atomicAdd(&bcur[b], h);
    }
    __syncthreads();
#pragma unroll
    for (int i = 0; i < 16; ++i) {
        int d = myd[i];
        if (d >= 0) {
            int b = d >> 6;
            int p = atomicAdd(&lcur[b], 1);
            epack[base[b] + p] = ((d & 63) << 16) | mys[i];
        }
    }
}

// ---------------- LDS-accumulated aggregation ----------------
// One block per 64-node bucket. acc[64][65] f32 (stride 65: bank-spread;
// col 64 = degree). 8 lanes/edge x 16B, ds_add_f32 accumulate, then
// normalize (+root+bias for MODE 1) and write bf16 rows coalesced.
// MODE 0: out[row*128 + c] = mean(x[src])            (ab1 cols 0:64)
// MODE 1: out[row*64 + c]  = mean(hw[src]) + hroot + b2
template <int MODE, int OS>
__global__ __launch_bounds__(256) void agg_lds(
    const unsigned short* __restrict__ tbl,   // gather table (stride 128)
    const int* __restrict__ gbase, const int* __restrict__ bcnt,
    const int* __restrict__ epack,
    const unsigned short* __restrict__ hwroot, const float* __restrict__ b2,
    unsigned short* __restrict__ outb, int N) {
    __shared__ float acc[64 * 65];
    int b = blockIdx.x, t = threadIdx.x;
    for (int i = t; i < 64 * 65; i += 256) acc[i] = 0.f;
    __syncthreads();
    const int ebase = gbase[b], ecnt = bcnt[b];
    const int lane = t & 63, w = t >> 6;
    const int slot = lane >> 3, c = lane & 7;
    const unsigned short* tb = tbl + c * 8;

    for (int i0 = 0; i0 < ecnt; i0 += 64) {
        int e0 = i0 + (w << 4) + slot;
        int e1 = e0 + 8;
        int p0 = 0, p1 = 0;
        uint4 v0, v1;
        bool g0 = e0 < ecnt, g1 = e1 < ecnt;
        if (g0) { p0 = epack[ebase + e0]; v0 = *(const uint4*)(tb + (size_t)(p0 & 0xFFFF) * 128); }
        if (g1) { p1 = epack[ebase + e1]; v1 = *(const uint4*)(tb + (size_t)(p1 & 0xFFFF) * 128); }
        if (g0) {
            float* a = acc + (p0 >> 16) * 65 + c * 8;
            atomicAdd(a + 0, bf2f((unsigned short)v0.x));
            atomicAdd(a + 1, bf2f((unsigned short)(v0.x >> 16)));
            atomicAdd(a + 2, bf2f((unsigned short)v0.y));
            atomicAdd(a + 3, bf2f((unsigned short)(v0.y >> 16)));
            atomicAdd(a + 4, bf2f((unsigned short)v0.z));
            atomicAdd(a + 5, bf2f((unsigned short)(v0.z >> 16)));
            atomicAdd(a + 6, bf2f((unsigned short)v0.w));
            atomicAdd(a + 7, bf2f((unsigned short)(v0.w >> 16)));
            if (c == 0) atomicAdd(acc + (p0 >> 16) * 65 + 64, 1.0f);
        }
        if (g1) {
            float* a = acc + (p1 >> 16) * 65 + c * 8;
            atomicAdd(a + 0, bf2f((unsigned short)v1.x));
            atomicAdd(a + 1, bf2f((unsigned short)(v1.x >> 16)));
            atomicAdd(a + 2, bf2f((unsigned short)v1.y));
            atomicAdd(a + 3, bf2f((unsigned short)(v1.y >> 16)));
            atomicAdd(a + 4, bf2f((unsigned short)v1.z));
            atomicAdd(a + 5, bf2f((unsigned short)(v1.z >> 16)));
            atomicAdd(a + 6, bf2f((unsigned short)v1.w));
            atomicAdd(a + 7, bf2f((unsigned short)(v1.w >> 16)));
            if (c == 0) atomicAdd(acc + (p1 >> 16) * 65 + 64, 1.0f);
        }
    }
    __syncthreads();

    int n0 = b << 6;
    for (int u = t; u < 512; u += 256) {
        int node = u >> 3, c8 = (u & 7) * 8;
        int row = n0 + node;
        if (row >= N) continue;
        float cnt = acc[node * 65 + 64];
        float inv = 1.0f / fmaxf(cnt, 1.0f);
        float v[8];
#pragma unroll
        for (int i = 0; i < 8; ++i) v[i] = acc[node * 65 + c8 + i] * inv;
        if (MODE == 1) {
            uint4 hr = *(const uint4*)(hwroot + (size_t)row * 128 + 64 + c8);
            v[0] += bf2f((unsigned short)hr.x)         + b2[c8 + 0];
            v[1] += bf2f((unsigned short)(hr.x >> 16)) + b2[c8 + 1];
            v[2] += bf2f((unsigned short)hr.y)         + b2[c8 + 2];
            v[3] += bf2f((unsigned short)(hr.y >> 16)) + b2[c8 + 3];
            v[4] += bf2f((unsigned short)hr.z)         + b2[c8 + 4];
            v[5] += bf2f((unsigned short)(hr.z >> 16)) + b2[c8 + 5];
            v[6] += bf2f((unsigned short)hr.w)         + b2[c8 + 6];
            v[7] += bf2f((unsigned short)(hr.w >> 16)) + b2[c8 + 7];
        }
        unsigned p0 = (unsigned)f2bf(v[0]) | ((unsigned)f2bf(v[1]) << 16);
        unsigned p1 = (unsigned)f2bf(v[2]) | ((unsigned)f2bf(v[3]) << 16);
        unsigned p2 = (unsigned)f2bf(v[4]) | ((unsigned)f2bf(v[5]) << 16);
        unsigned p3 = (unsigned)f2bf(v[6]) | ((unsigned)f2bf(v[7]) << 16);
        uint4 o; o.x = p0; o.y = p1; o.z = p2; o.w = p3;
        *(uint4*)(outb + (size_t)row * OS + c8) = o;
    }
}

// ---------------- fused double-GEMM ----------------
// Stage 1: T = relu(A @ Wp1 + bias1)  (A: n x K1 bf16, T: 64 x 256 tile in LDS)
// Stage 2: C = T @ Wp2 (+ bias2)      (C: n x (NBW2*64))
template <int K1, int NBW2, bool OUTBF>
__global__ __launch_bounds__(256) void gemm_fused(
    const unsigned short* __restrict__ A,
    const unsigned short* __restrict__ Bp1, const float* __restrict__ bias1,
    const unsigned short* __restrict__ Bp2, const float* __restrict__ bias2,
    void* __restrict__ Cv, int n)
{
    constexpr int KS1 = K1 / 32;
    constexpr int N2 = NBW2 * 64;
    constexpr int NB2 = NBW2 * 4;
    __shared__ unsigned short ht[64][264];

    const int m0 = blockIdx.x * 64;
    const int lane = threadIdx.x & 63;
    const int w = threadIdx.x >> 6;
    const int quad = lane >> 4;
    const int l16 = lane & 15;

    // ---- stage 1 ----
    {
        f32x4 acc[4][4] = {};
        const unsigned short* Arow = A + (size_t)(m0 + l16) * K1 + quad * 8;
        for (int s = 0; s < KS1; ++s) {
            bf16x8 a[4];
#pragma unroll
            for (int mb = 0; mb < 4; ++mb)
                a[mb] = *(const bf16x8*)(Arow + (size_t)mb * 16 * K1 + s * 32);
#pragma unroll
            for (int jn = 0; jn < 4; ++jn) {
                int j = w * 4 + jn;
                bf16x8 b = *(const bf16x8*)(Bp1 + ((size_t)(s * 16 + j) * 64 + lane) * 8);
#pragma unroll
                for (int mb = 0; mb < 4; ++mb)
                    acc[mb][jn] = __builtin_amdgcn_mfma_f32_16x16x32_bf16(a[mb], b, acc[mb][jn], 0, 0, 0);
            }
        }
#pragma unroll
        for (int jn = 0; jn < 4; ++jn) {
            int col = (w * 4 + jn) * 16 + l16;
            float bv = bias1[col];
#pragma unroll
            for (int mb = 0; mb < 4; ++mb)
#pragma unroll
                for (int r = 0; r < 4; ++r) {
                    int row = mb * 16 + quad * 4 + r;
                    ht[row][col] = f2bf(fmaxf(acc[mb][jn][r] + bv, 0.f));
                }
        }
    }
    __syncthreads();

    // ---- stage 2 ----
    {
        f32x4 acc[4][NBW2] = {};
        for (int s = 0; s < 8; ++s) {
            bf16x8 a[4];
#pragma unroll
            for (int mb = 0; mb < 4; ++mb)
                a[mb] = *(const bf16x8*)&ht[mb * 16 + l16][s * 32 + quad * 8];
#pragma unroll
            for (int jn = 0; jn < NBW2; ++jn) {
                int j = w * NBW2 + jn;
                bf16x8 b = *(const bf16x8*)(Bp2 + ((size_t)(s * NB2 + j) * 64 + lane) * 8);
#pragma unroll
                for (int mb = 0; mb < 4; ++mb)
                    acc[mb][jn] = __builtin_amdgcn_mfma_f32_16x16x32_bf16(a[mb], b, acc[mb][jn], 0, 0, 0);
            }
        }
#pragma unroll
        for (int jn = 0; jn < NBW2; ++jn) {
            int col = (w * NBW2 + jn) * 16 + l16;
            float bv = bias2 ? bias2[col] : 0.f;
#pragma unroll
            for (int mb = 0; mb < 4; ++mb)
#pragma unroll
                for (int r = 0; r < 4; ++r) {
                    int row = m0 + mb * 16 + quad * 4 + r;
                    if (row < n) {
                        float v = acc[mb][jn][r] + bv;
                        if (OUTBF)
                            ((unsigned short*)Cv)[(size_t)row * N2 + col] = f2bf(v);
                        else
                            ((float*)Cv)[(size_t)row * N2 + col] = v;
                    }
                }
        }
    }
}

extern "C" void kernel_launch(void* const* d_in, const int* in_sizes, int n_in,
                              void* d_out, int out_size, void* d_ws, size_t ws_size,
                              hipStream_t stream) {
    const float* x      = (const float*)d_in[0];
    const int*   ei     = (const int*)d_in[1];
    const float* W1g    = (const float*)d_in[2];   // (8,64,256): [0] = first 16384
    const float* root1  = (const float*)d_in[3];
    const float* b1     = (const float*)d_in[4];
    const float* W2g    = (const float*)d_in[5];   // (8,256,64): [0] = first 16384
    const float* root2  = (const float*)d_in[6];
    const float* b2     = (const float*)d_in[7];
    const float* dw1    = (const float*)d_in[8];
    const float* db1    = (const float*)d_in[9];
    const float* dw2    = (const float*)d_in[10];
    const float* db2    = (const float*)d_in[11];
    float* out = (float*)d_out;

    const int N = in_sizes[0] / 64;
    const int E = in_sizes[1] / 2;
    const int Npad = N + 64;
    const int* srcv = ei;
    const int* dstv = ei + E;

    char* ws = (char*)d_ws;
    auto alloc = [&](size_t bytes) -> void* {
        void* p = (void*)ws;
        ws += (bytes + 255) & ~(size_t)255;
        return p;
    };
    int*   bcnt   = (int*)alloc(4096);               // per-bucket counts (1024)
    int*   bcur   = (int*)alloc(4096);               // partition cursors
    int*   gbase  = (int*)alloc(4096);               // exclusive-scan bases
    int*   epack  = (int*)alloc((size_t)E * 4);
    unsigned short* Pb1 = (unsigned short*)alloc(32768 * 2);
    unsigned short* Pb2 = (unsigned short*)alloc(32768 * 2);
    unsigned short* Pd1 = (unsigned short*)alloc(16384 * 2);
    unsigned short* Pd2 = (unsigned short*)alloc(16384 * 2);
    unsigned short* ab1    = (unsigned short*)alloc((size_t)Npad * 128 * 2);  // [agg1 | xb]
    unsigned short* hwroot = (unsigned short*)alloc((size_t)Npad * 128 * 2);
    unsigned short* z      = (unsigned short*)alloc((size_t)Npad * 64 * 2);

    hipMemsetAsync(bcnt, 0, 8192, stream);           // bcnt + bcur (adjacent)

    int gb = (N + 63) / 64;
    int nbk = (N + 63) / 64;                         // 64-node buckets
    int pa = (E + 4095) / 4096;
    int pb_pack = (98304 + N * 16 + THREADS - 1) / THREADS;

    // packs + x->bf16 + bucket histogram (one kernel, disjoint block ranges)
    prep_kernel<<<pb_pack + pa, THREADS, 0, stream>>>(
        W1g, root1, W2g, root2, dw1, dw2, x, dstv, bcnt,
        Pb1, Pb2, Pd1, Pd2, ab1, N, E, pb_pack);
    // bucket bases + edge partition (packed (dst&63)<<16|src)
    scan_buckets<<<1, 512, 0, stream>>>(bcnt, gbase);
    partition_edges<<<pa, 256, 0, stream>>>(srcv, dstv, gbase, bcur, epack, E);

    // layer 1: LDS-accumulated mean agg, then fused [L1 GEMM -> L2 projection]
    agg_lds<0, 128><<<nbk, 256, 0, stream>>>(ab1 + 64, gbase, bcnt, epack,
                                             nullptr, nullptr, ab1, N);
    gemm_fused<128, 2, true><<<gb, 256, 0, stream>>>(ab1, Pb1, b1, Pb2, nullptr, hwroot, N);
    // layer 2: LDS-accumulated agg + root + bias epilogue
    agg_lds<1, 64><<<nbk, 256, 0, stream>>>(hwroot, gbase, bcnt, epack,
                                            hwroot, b2, z, N);
    // fused decoder [dec1 -> dec2]
    gemm_fused<64, 1, false><<<gb, 256, 0, stream>>>(z, Pd1, db1, Pd2, db2, out, N);
}

// Round 4
// 199.028 us; speedup vs baseline: 4.2486x; 4.2486x over previous
//
#include <hip/hip_runtime.h>
#include <hip/hip_bf16.h>

// GraphAE: pseudo == 0 => only W[0] of the 8 spline matrices matters.
// Linearization: mean(h[src])@W2_0 == mean(h[src]@W2_0) -> project before gather.
// Round 13:
//  - R12 LDS-atomic agg reverted (350us: 51M ds-atomic serialization).
//  - Back to R9 CSR structure, but wave-starved phases widened:
//    partition_edges 196x256 (784 waves) -> 391x512 (3128 waves),
//    bucket_fill2    196x256 (784 waves) -> 196x1024 (3136 waves).
//    Same algorithm, 4x latency hiding.
//  - aggs: R11's 16B/lane gather (8 lanes/edge x 8 slots, shfl 8/16/32).
//
// Verified MFMA layouts (guide §3): A[m=lane&15][k=(lane>>4)*8+j],
// B[k=(lane>>4)*8+j][n=lane&15], D[row=(lane>>4)*4+r][col=lane&15].

#define THREADS 256

typedef __attribute__((ext_vector_type(8))) short bf16x8;   // 8 bf16 = 4 VGPRs
typedef __attribute__((ext_vector_type(4))) float f32x4;    // acc

__device__ __forceinline__ float bf2f(unsigned short u) {
    unsigned v = ((unsigned)u) << 16;
    return __builtin_bit_cast(float, v);
}
__device__ __forceinline__ unsigned short f2bf(float f) {
    __hip_bfloat16 h = __float2bfloat16(f);   // RNE
    return __builtin_bit_cast(unsigned short, h);
}
__device__ __forceinline__ void acc8(float* f, uint4 v) {
    f[0] += bf2f((unsigned short)v.x); f[1] += bf2f((unsigned short)(v.x >> 16));
    f[2] += bf2f((unsigned short)v.y); f[3] += bf2f((unsigned short)(v.y >> 16));
    f[4] += bf2f((unsigned short)v.z); f[5] += bf2f((unsigned short)(v.z >> 16));
    f[6] += bf2f((unsigned short)v.w); f[7] += bf2f((unsigned short)(v.w >> 16));
}

// ---------------- weight pack ----------------
// Pack fp32 W (eff. K x NOUT) into MFMA B-frag layout bf16:
// dst[(((s*NB + j)*64 + lane)*8 + i] = W[s*32 + (lane>>4)*8 + i][j*16 + (lane&15)]
__device__ __forceinline__ void pack_one(unsigned short* dst,
                                         const float* W0, const float* W1,
                                         int NB, int ksplit, int colsplit,
                                         int ld0, int ld1, int t) {
    int i = t & 7, lane = (t >> 3) & 63, rest = t >> 9;
    int j = rest % NB, s = rest / NB;
    int k = s * 32 + ((lane >> 4) << 3) + i;
    int c = (j << 4) + (lane & 15);
    float v;
    if (c >= colsplit)    v = W1[(size_t)k * ld1 + (c - colsplit)];
    else if (k >= ksplit) v = W1[(size_t)(k - ksplit) * ld1 + c];
    else                  v = W0[(size_t)k * ld0 + c];
    dst[t] = f2bf(v);
}

#define BIG (1 << 30)

// prep: weight packs + x->bf16 (vectorized) + bucket histogram (edge blocks)
__global__ void prep_kernel(const float* __restrict__ W1g, const float* __restrict__ root1,
                            const float* __restrict__ W2g, const float* __restrict__ root2,
                            const float* __restrict__ dw1, const float* __restrict__ dw2,
                            const float* __restrict__ x, const int* __restrict__ dstv,
                            int* __restrict__ bcnt,
                            unsigned short* __restrict__ Pb1,   // 128x256
                            unsigned short* __restrict__ Pb2,   // 256x128
                            unsigned short* __restrict__ Pd1,   // 64x256
                            unsigned short* __restrict__ Pd2,   // 256x64
                            unsigned short* __restrict__ ab1,   // N x 128, x -> cols 64:128
                            int n, int E, int pb_pack) {
    if ((int)blockIdx.x >= pb_pack) {
        __shared__ int hist[256];
        int t = threadIdx.x;
        hist[t] = 0;
        __syncthreads();
        int e0 = ((int)blockIdx.x - pb_pack) * 4096;
#pragma unroll
        for (int i = 0; i < 16; ++i) {
            int e = e0 + t + i * 256;
            if (e < E) atomicAdd(&hist[dstv[e] >> 8], 1);
        }
        __syncthreads();
        int h = hist[t];
        if (h) atomicAdd(&bcnt[t], h);
        return;
    }
    int t = blockIdx.x * blockDim.x + threadIdx.x;
    if (t < 32768) {
        pack_one(Pb1, W1g, root1, 16, 64, BIG, 256, 256, t);
    } else if (t < 65536) {
        pack_one(Pb2, W2g, root2, 8, BIG, 64, 64, 64, t - 32768);
    } else if (t < 81920) {
        pack_one(Pd1, dw1, dw1, 16, BIG, BIG, 256, 256, t - 65536);
    } else if (t < 98304) {
        pack_one(Pd2, dw2, dw2, 4, BIG, BIG, 64, 64, t - 81920);
    } else if (t < 98304 + n * 16) {
        int u = t - 98304;
        int row = u >> 4, c4 = (u & 15) * 4;
        float4 v = *(const float4*)(x + (size_t)row * 64 + c4);
        unsigned lo = (unsigned)f2bf(v.x) | ((unsigned)f2bf(v.y) << 16);
        unsigned hi = (unsigned)f2bf(v.z) | ((unsigned)f2bf(v.w) << 16);
        uint2 o; o.x = lo; o.y = hi;
        *(uint2*)(ab1 + (size_t)row * 128 + 64 + c4) = o;
    }
}

// Pass A: partition edges into buckets of 256 consecutive dst nodes.
// 512 threads x 2048 edges/block (391 blocks, 3128 waves) for latency hiding.
__global__ __launch_bounds__(512) void partition_edges(
    const int* __restrict__ src, const int* __restrict__ dst,
    const int* __restrict__ bcnt, int* __restrict__ bcur,
    int* __restrict__ epack, int E) {
    __shared__ int hist[256];
    __shared__ int base[256];
    __shared__ int lcur[256];
    __shared__ int bb[256];
    int t = threadIdx.x;
    if (t < 256) { hist[t] = 0; lcur[t] = 0; }
    __syncthreads();
    int e0 = blockIdx.x * 2048;
    int myd[4], mys[4];
#pragma unroll
    for (int i = 0; i < 4; ++i) {
        int e = e0 + t + i * 512;
        int d = (e < E) ? dst[e] : -1;
        mys[i] = (e < E) ? src[e] : 0;
        myd[i] = d;
        if (d >= 0) atomicAdd(&hist[d >> 8], 1);
    }
    // local exclusive scan of bcnt -> bucket bases (t<256 active)
    int cb = 0;
    if (t < 256) { cb = bcnt[t]; bb[t] = cb; }
    __syncthreads();
    for (int off = 1; off < 256; off <<= 1) {
        int xv = (t >= off && t < 256) ? bb[t - off] : 0;
        __syncthreads();
        if (t < 256) bb[t] += xv;
        __syncthreads();
    }
    if (t < 256) {
        int h = hist[t];
        if (h > 0) base[t] = (bb[t] - cb) + atomicAdd(&bcur[t], h);
    }
    __syncthreads();
#pragma unroll
    for (int i = 0; i < 4; ++i) {
        int d = myd[i];
        if (d >= 0) {
            int b = d >> 8;
            int p = atomicAdd(&lcur[b], 1);
            epack[base[b] + p] = ((d & 255) << 20) | mys[i];
        }
    }
}

// Pass B: one block (1024 threads, 16 waves) per 256-node bucket.
// Local per-node histogram + scan in LDS (emits offs and invd), then
// bucket-local ordering + coalesced esrc write.
__global__ __launch_bounds__(1024) void bucket_fill2(
    const int* __restrict__ epack, const int* __restrict__ bcnt,
    int* __restrict__ offs, float* __restrict__ invd,
    int* __restrict__ esrc, int N) {
    __shared__ int sb_[256];
    __shared__ int nh[256];
    __shared__ int loff[256];
    __shared__ int ncur[256];
    __shared__ int stage[8192];
    int b = blockIdx.x, t = threadIdx.x;
    int n0 = b << 8;
    // bucket base via local scan of bcnt
    int cb = 0;
    if (t < 256) { cb = bcnt[t]; sb_[t] = cb; }
    __syncthreads();
    for (int off = 1; off < 256; off <<= 1) {
        int xv = (t >= off && t < 256) ? sb_[t - off] : 0;
        __syncthreads();
        if (t < 256) sb_[t] += xv;
        __syncthreads();
    }
    int ebase = b ? sb_[b - 1] : 0;
    int ecount = sb_[b] - ebase;
    if (b == 0 && t == 0) offs[N] = sb_[255];
    if (t < 256) nh[t] = 0;
    __syncthreads();
    for (int i = t; i < ecount; i += 1024)
        atomicAdd(&nh[epack[ebase + i] >> 20], 1);
    __syncthreads();
    int v = 0;
    if (t < 256) { v = nh[t]; loff[t] = v; }
    __syncthreads();
    for (int off = 1; off < 256; off <<= 1) {
        int xv = (t >= off && t < 256) ? loff[t - off] : 0;
        __syncthreads();
        if (t < 256) loff[t] += xv;
        __syncthreads();
    }
    if (t < 256) {
        int ex = loff[t] - v;
        loff[t] = ex;
        int node = n0 + t;
        if (node < N) {
            offs[node] = ebase + ex;
            invd[node] = 1.0f / (float)max(v, 1);
        }
        ncur[t] = 0;
    }
    __syncthreads();
    bool useLds = (ecount <= 8192);
    for (int i = t; i < ecount; i += 1024) {
        int p = epack[ebase + i];
        int dl = p >> 20;
        int pos = atomicAdd(&ncur[dl], 1);
        int g = loff[dl] + pos;         // bucket-local slot
        int sv = p & 0xFFFFF;
        if (useLds) stage[g] = sv;
        else        esrc[ebase + g] = sv;
    }
    __syncthreads();
    if (useLds)
        for (int i = t; i < ecount; i += 1024) esrc[ebase + i] = stage[i];
}

// ---------------- gathers: 16B/lane, 8 edges per wave-instr, 16-edge unroll ----
// lane = slot(8) x c(8); lane loads features [c*8, c*8+8) of edge (j+slot).
// agg1 = mean(x[src]): reads ab1 cols 64:128, writes ab1 cols 0:64.
__global__ void agg_x4(unsigned short* __restrict__ ab1, const int* __restrict__ esrc,
                       const int* __restrict__ offs, const float* __restrict__ invd,
                       int n) {
    int node = blockIdx.x * 4 + (threadIdx.x >> 6);
    if (node >= n) return;
    int l = threadIdx.x & 63;
    int slot = l >> 3, c = l & 7;
    const unsigned short* xb = ab1 + 64 + c * 8;
    int s = offs[node], e = offs[node + 1];
    float a0[8] = {}, a1[8] = {};
    int j = s;
    for (; j + 16 <= e; j += 16) {
        int i0 = esrc[j + slot], i1 = esrc[j + 8 + slot];
        uint4 v0 = *(const uint4*)(xb + (size_t)i0 * 128);
        uint4 v1 = *(const uint4*)(xb + (size_t)i1 * 128);
        acc8(a0, v0); acc8(a1, v1);
    }
    if (j + 8 <= e) {
        int i0 = esrc[j + slot];
        uint4 v0 = *(const uint4*)(xb + (size_t)i0 * 128);
        acc8(a0, v0);
        j += 8;
    }
    if (slot < e - j) {
        int i0 = esrc[j + slot];
        uint4 v0 = *(const uint4*)(xb + (size_t)i0 * 128);
        acc8(a1, v0);
    }
    float r[8];
#pragma unroll
    for (int k = 0; k < 8; ++k) {
        r[k] = a0[k] + a1[k];
        r[k] += __shfl_xor(r[k], 8);
        r[k] += __shfl_xor(r[k], 16);
        r[k] += __shfl_xor(r[k], 32);
    }
    if (slot == 0) {
        float iv = invd[node];
        unsigned p0 = (unsigned)f2bf(r[0] * iv) | ((unsigned)f2bf(r[1] * iv) << 16);
        unsigned p1 = (unsigned)f2bf(r[2] * iv) | ((unsigned)f2bf(r[3] * iv) << 16);
        unsigned p2 = (unsigned)f2bf(r[4] * iv) | ((unsigned)f2bf(r[5] * iv) << 16);
        unsigned p3 = (unsigned)f2bf(r[6] * iv) | ((unsigned)f2bf(r[7] * iv) << 16);
        uint4 o; o.x = p0; o.y = p1; o.z = p2; o.w = p3;
        *(uint4*)(ab1 + (size_t)node * 128 + c * 8) = o;
    }
}

// z = mean(hw[src]) + hroot + b2 ; hwroot N x 128 bf16 (0:64 hw, 64:128 hroot)
__global__ void agg_z4(const unsigned short* __restrict__ hwroot,
                       const int* __restrict__ esrc, const int* __restrict__ offs,
                       const float* __restrict__ invd, const float* __restrict__ b2,
                       unsigned short* __restrict__ z, int n) {
    int node = blockIdx.x * 4 + (threadIdx.x >> 6);
    if (node >= n) return;
    int l = threadIdx.x & 63;
    int slot = l >> 3, c = l & 7;
    const unsigned short* hb = hwroot + c * 8;
    int s = offs[node], e = offs[node + 1];
    float a0[8] = {}, a1[8] = {};
    int j = s;
    for (; j + 16 <= e; j += 16) {
        int i0 = esrc[j + slot], i1 = esrc[j + 8 + slot];
        uint4 v0 = *(const uint4*)(hb + (size_t)i0 * 128);
        uint4 v1 = *(const uint4*)(hb + (size_t)i1 * 128);
        acc8(a0, v0); acc8(a1, v1);
    }
    if (j + 8 <= e) {
        int i0 = esrc[j + slot];
        uint4 v0 = *(const uint4*)(hb + (size_t)i0 * 128);
        acc8(a0, v0);
        j += 8;
    }
    if (slot < e - j) {
        int i0 = esrc[j + slot];
        uint4 v0 = *(const uint4*)(hb + (size_t)i0 * 128);
        acc8(a1, v0);
    }
    float r[8];
#pragma unroll
    for (int k = 0; k < 8; ++k) {
        r[k] = a0[k] + a1[k];
        r[k] += __shfl_xor(r[k], 8);
        r[k] += __shfl_xor(r[k], 16);
        r[k] += __shfl_xor(r[k], 32);
    }
    if (slot == 0) {
        float iv = invd[node];
        uint4 hr = *(const uint4*)(hwroot + (size_t)node * 128 + 64 + c * 8);
        float4 bA = *(const float4*)(b2 + c * 8);
        float4 bB = *(const float4*)(b2 + c * 8 + 4);
        float v0 = r[0] * iv + bf2f((unsigned short)hr.x) + bA.x;
        float v1 = r[1] * iv + bf2f((unsigned short)(hr.x >> 16)) + bA.y;
        float v2 = r[2] * iv + bf2f((unsigned short)hr.y) + bA.z;
        float v3 = r[3] * iv + bf2f((unsigned short)(hr.y >> 16)) + bA.w;
        float v4 = r[4] * iv + bf2f((unsigned short)hr.z) + bB.x;
        float v5 = r[5] * iv + bf2f((unsigned short)(hr.z >> 16)) + bB.y;
        float v6 = r[6] * iv + bf2f((unsigned short)hr.w) + bB.z;
        float v7 = r[7] * iv + bf2f((unsigned short)(hr.w >> 16)) + bB.w;
        unsigned p0 = (unsigned)f2bf(v0) | ((unsigned)f2bf(v1) << 16);
        unsigned p1 = (unsigned)f2bf(v2) | ((unsigned)f2bf(v3) << 16);
        unsigned p2 = (unsigned)f2bf(v4) | ((unsigned)f2bf(v5) << 16);
        unsigned p3 = (unsigned)f2bf(v6) | ((unsigned)f2bf(v7) << 16);
        uint4 o; o.x = p0; o.y = p1; o.z = p2; o.w = p3;
        *(uint4*)(z + (size_t)node * 64 + c * 8) = o;
    }
}

// ---------------- fused double-GEMM ----------------
// Stage 1: T = relu(A @ Wp1 + bias1)  (A: n x K1 bf16, T: 64 x 256 tile in LDS)
// Stage 2: C = T @ Wp2 (+ bias2)      (C: n x (NBW2*64))
template <int K1, int NBW2, bool OUTBF>
__global__ __launch_bounds__(256) void gemm_fused(
    const unsigned short* __restrict__ A,
    const unsigned short* __restrict__ Bp1, const float* __restrict__ bias1,
    const unsigned short* __restrict__ Bp2, const float* __restrict__ bias2,
    void* __restrict__ Cv, int n)
{
    constexpr int KS1 = K1 / 32;
    constexpr int N2 = NBW2 * 64;
    constexpr int NB2 = NBW2 * 4;
    __shared__ unsigned short ht[64][264];

    const int m0 = blockIdx.x * 64;
    const int lane = threadIdx.x & 63;
    const int w = threadIdx.x >> 6;
    const int quad = lane >> 4;
    const int l16 = lane & 15;

    // ---- stage 1 ----
    {
        f32x4 acc[4][4] = {};
        const unsigned short* Arow = A + (size_t)(m0 + l16) * K1 + quad * 8;
        for (int s = 0; s < KS1; ++s) {
            bf16x8 a[4];
#pragma unroll
            for (int mb = 0; mb < 4; ++mb)
                a[mb] = *(const bf16x8*)(Arow + (size_t)mb * 16 * K1 + s * 32);
#pragma unroll
            for (int jn = 0; jn < 4; ++jn) {
                int j = w * 4 + jn;
                bf16x8 b = *(const bf16x8*)(Bp1 + ((size_t)(s * 16 + j) * 64 + lane) * 8);
#pragma unroll
                for (int mb = 0; mb < 4; ++mb)
                    acc[mb][jn] = __builtin_amdgcn_mfma_f32_16x16x32_bf16(a[mb], b, acc[mb][jn], 0, 0, 0);
            }
        }
#pragma unroll
        for (int jn = 0; jn < 4; ++jn) {
            int col = (w * 4 + jn) * 16 + l16;
            float bv = bias1[col];
#pragma unroll
            for (int mb = 0; mb < 4; ++mb)
#pragma unroll
                for (int r = 0; r < 4; ++r) {
                    int row = mb * 16 + quad * 4 + r;
                    ht[row][col] = f2bf(fmaxf(acc[mb][jn][r] + bv, 0.f));
                }
        }
    }
    __syncthreads();

    // ---- stage 2 ----
    {
        f32x4 acc[4][NBW2] = {};
        for (int s = 0; s < 8; ++s) {
            bf16x8 a[4];
#pragma unroll
            for (int mb = 0; mb < 4; ++mb)
                a[mb] = *(const bf16x8*)&ht[mb * 16 + l16][s * 32 + quad * 8];
#pragma unroll
            for (int jn = 0; jn < NBW2; ++jn) {
                int j = w * NBW2 + jn;
                bf16x8 b = *(const bf16x8*)(Bp2 + ((size_t)(s * NB2 + j) * 64 + lane) * 8);
#pragma unroll
                for (int mb = 0; mb < 4; ++mb)
                    acc[mb][jn] = __builtin_amdgcn_mfma_f32_16x16x32_bf16(a[mb], b, acc[mb][jn], 0, 0, 0);
            }
        }
#pragma unroll
        for (int jn = 0; jn < NBW2; ++jn) {
            int col = (w * NBW2 + jn) * 16 + l16;
            float bv = bias2 ? bias2[col] : 0.f;
#pragma unroll
            for (int mb = 0; mb < 4; ++mb)
#pragma unroll
                for (int r = 0; r < 4; ++r) {
                    int row = m0 + mb * 16 + quad * 4 + r;
                    if (row < n) {
                        float v = acc[mb][jn][r] + bv;
                        if (OUTBF)
                            ((unsigned short*)Cv)[(size_t)row * N2 + col] = f2bf(v);
                        else
                            ((float*)Cv)[(size_t)row * N2 + col] = v;
                    }
                }
        }
    }
}

extern "C" void kernel_launch(void* const* d_in, const int* in_sizes, int n_in,
                              void* d_out, int out_size, void* d_ws, size_t ws_size,
                              hipStream_t stream) {
    const float* x      = (const float*)d_in[0];
    const int*   ei     = (const int*)d_in[1];
    const float* W1g    = (const float*)d_in[2];   // (8,64,256): [0] = first 16384
    const float* root1  = (const float*)d_in[3];
    const float* b1     = (const float*)d_in[4];
    const float* W2g    = (const float*)d_in[5];   // (8,256,64): [0] = first 16384
    const float* root2  = (const float*)d_in[6];
    const float* b2     = (const float*)d_in[7];
    const float* dw1    = (const float*)d_in[8];
    const float* db1    = (const float*)d_in[9];
    const float* dw2    = (const float*)d_in[10];
    const float* db2    = (const float*)d_in[11];
    float* out = (float*)d_out;

    const int N = in_sizes[0] / 64;
    const int E = in_sizes[1] / 2;
    const int Npad = N + 64;
    const int* srcv = ei;
    const int* dstv = ei + E;

    char* ws = (char*)d_ws;
    auto alloc = [&](size_t bytes) -> void* {
        void* p = (void*)ws;
        ws += (bytes + 255) & ~(size_t)255;
        return p;
    };
    int*   bcnt   = (int*)alloc(1024);               // per-bucket counts (256)
    int*   bcur   = (int*)alloc(1024);               // 0-based bucket cursors
    int*   offs   = (int*)alloc((size_t)(N + 1) * 4);
    float* invd   = (float*)alloc((size_t)N * 4);
    int*   esrc   = (int*)alloc((size_t)E * 4);
    int*   epack  = (int*)alloc((size_t)E * 4);
    unsigned short* Pb1 = (unsigned short*)alloc(32768 * 2);
    unsigned short* Pb2 = (unsigned short*)alloc(32768 * 2);
    unsigned short* Pd1 = (unsigned short*)alloc(16384 * 2);
    unsigned short* Pd2 = (unsigned short*)alloc(16384 * 2);
    unsigned short* ab1    = (unsigned short*)alloc((size_t)Npad * 128 * 2);  // [agg1 | xb]
    unsigned short* hwroot = (unsigned short*)alloc((size_t)Npad * 128 * 2);
    unsigned short* z      = (unsigned short*)alloc((size_t)Npad * 64 * 2);

    hipMemsetAsync(bcnt, 0, 2048, stream);           // bcnt + bcur (adjacent)

    int gb = (N + 63) / 64;
    int nbkt = (N + 255) / 256;
    int pa = (E + 4095) / 4096;
    int pa2 = (E + 2047) / 2048;
    int pb_pack = (98304 + N * 16 + THREADS - 1) / THREADS;

    // packs + x->bf16 + bucket histogram (one kernel, disjoint block ranges)
    prep_kernel<<<pb_pack + pa, THREADS, 0, stream>>>(
        W1g, root1, W2g, root2, dw1, dw2, x, dstv, bcnt,
        Pb1, Pb2, Pd1, Pd2, ab1, N, E, pb_pack);
    // bucket-level CSR (bases computed locally from bcnt in each kernel)
    partition_edges<<<pa2, 512, 0, stream>>>(srcv, dstv, bcnt, bcur, epack, E);
    bucket_fill2<<<nbkt, 1024, 0, stream>>>(epack, bcnt, offs, invd, esrc, N);

    // layer 1 agg + fused [L1 GEMM -> L2 projection]
    agg_x4<<<(N + 3) / 4, THREADS, 0, stream>>>(ab1, esrc, offs, invd, N);
    gemm_fused<128, 2, true><<<gb, 256, 0, stream>>>(ab1, Pb1, b1, Pb2, nullptr, hwroot, N);
    // layer 2 gather + epilogue
    agg_z4<<<(N + 3) / 4, THREADS, 0, stream>>>(hwroot, esrc, offs, invd, b2, z, N);
    // fused decoder [dec1 -> dec2]
    gemm_fused<64, 1, false><<<gb, 256, 0, stream>>>(z, Pd1, db1, Pd2, db2, out, N);
}